// Round 1
// baseline (13111.987 us; speedup 1.0000x reference)
//
#include <hip/hip_runtime.h>
#include <hip/hip_bf16.h>
#include <cstdint>

// ---------------------------------------------------------------------------
// Sparse-masked 3D CNN, fp32 reference-accurate implementation.
// Layout: channel-last (z,y,x,c). Masks stored as float 0/1.
// ---------------------------------------------------------------------------

__global__ void scatter_kernel(const float* __restrict__ feats,
                               const int* __restrict__ coors,
                               float* __restrict__ dense,
                               float* __restrict__ mask, int n)
{
    int i = blockIdx.x * blockDim.x + threadIdx.x;
    if (i >= n) return;
    const int z = coors[i * 4 + 1];
    const int y = coors[i * 4 + 2];
    const int x = coors[i * 4 + 3];
    const size_t s = (size_t)((z * 64 + y) * 64 + x);
    dense[s * 3 + 0] = feats[i * 3 + 0];
    dense[s * 3 + 1] = feats[i * 3 + 1];
    dense[s * 3 + 2] = feats[i * 3 + 2];
    mask[s] = 1.f;
}

// Generic masked conv, kernel (3,5,5), pad (1,2,2).
// Block: COUT*G threads; one (z,y) output row per block.
// Thread t: co = t % COUT, x-segment [xb, xb+XT).
// LDS stages 15 rows (kz,ky) x (S+4 padded x) x CIC input channels.
template<int CIN, int COUT, int S, int CIC, int G>
__global__ __launch_bounds__(COUT * G)
void conv_kernel(const float* __restrict__ in, const float* __restrict__ w,
                 const float* __restrict__ mask, float* __restrict__ out)
{
    constexpr int XT = S / G;
    constexpr int SP = S + 4;
    constexpr int NT = COUT * G;
    __shared__ float lds[15 * SP * CIC];

    const int y = blockIdx.x;
    const int z = blockIdx.y;
    const int t = threadIdx.x;
    const int co = t % COUT;
    const int xb = (t / COUT) * XT;

    float acc[XT];
#pragma unroll
    for (int i = 0; i < XT; ++i) acc[i] = 0.f;

    constexpr int NCHUNK = CIN / CIC;
#pragma unroll 1
    for (int cc = 0; cc < NCHUNK; ++cc) {
        __syncthreads();
        constexpr int TOTAL = 15 * SP * CIC;
        for (int idx = t; idx < TOTAL; idx += NT) {
            const int r   = idx / (SP * CIC);
            const int rem = idx - r * (SP * CIC);
            const int xx  = rem / CIC;
            const int ci  = rem - xx * CIC;
            const int kz = r / 5, ky = r - kz * 5;
            const int zz = z + kz - 1;
            const int yy = y + ky - 2;
            const int xi = xx - 2;
            float v = 0.f;
            if (zz >= 0 && zz < S && yy >= 0 && yy < S && xi >= 0 && xi < S)
                v = in[(size_t)((zz * S + yy) * S + xi) * CIN + cc * CIC + ci];
            lds[idx] = v;
        }
        __syncthreads();

#pragma unroll
        for (int kz = 0; kz < 3; ++kz)
#pragma unroll
        for (int ky = 0; ky < 5; ++ky) {
            const float* lrow = &lds[(kz * 5 + ky) * SP * CIC];
            const float* wrow = w + (size_t)((kz * 5 + ky) * 5) * CIN * COUT
                                  + (size_t)cc * CIC * COUT + co;
#pragma unroll 1
            for (int ci = 0; ci < CIC; ++ci) {
                float inv[XT + 4];
#pragma unroll
                for (int j = 0; j < XT + 4; ++j)
                    inv[j] = lrow[(xb + j) * CIC + ci];
                const float* wp = wrow + (size_t)ci * COUT;
#pragma unroll
                for (int kx = 0; kx < 5; ++kx) {
                    const float wv = wp[(size_t)kx * CIN * COUT];
#pragma unroll
                    for (int i = 0; i < XT; ++i)
                        acc[i] += inv[i + kx] * wv;
                }
            }
        }
    }

#pragma unroll
    for (int i = 0; i < XT; ++i) {
        const int x = xb + i;
        const float m = mask[(z * S + y) * S + x];
        out[(size_t)((z * S + y) * S + x) * COUT + co] = (m > 0.f) ? acc[i] : 0.f;
    }
}

// Sparse maxpool 2x2x2 with reference semantics (-1e30 substitution).
__global__ void pool_kernel(const float* __restrict__ in, const float* __restrict__ mi,
                            float* __restrict__ out, float* __restrict__ mo,
                            int S, int C)
{
    const int So = S >> 1;
    const long long total = (long long)So * So * So * C;
    for (long long i = blockIdx.x * (long long)blockDim.x + threadIdx.x; i < total;
         i += (long long)gridDim.x * blockDim.x) {
        const int c = (int)(i % C);
        const long long s = i / C;
        const int xo = (int)(s % So);
        const int yo = (int)((s / So) % So);
        const int zo = (int)(s / ((long long)So * So));
        float best = -1e30f;
        float m2 = 0.f;
        for (int dz = 0; dz < 2; ++dz)
            for (int dy = 0; dy < 2; ++dy)
                for (int dx = 0; dx < 2; ++dx) {
                    const int zi = zo * 2 + dz, yi = yo * 2 + dy, xi = xo * 2 + dx;
                    const float m = mi[(zi * S + yi) * S + xi];
                    if (m > 0.f) {
                        m2 = 1.f;
                        best = fmaxf(best, in[(size_t)((zi * S + yi) * S + xi) * C + c]);
                    }
                }
        out[i] = (m2 > 0.f) ? best : 0.f;
        if (c == 0) mo[s] = m2;
    }
}

// Final two convs at 1x1x1 spatial: only center tap (kz=1,ky=2,kx=2) = index 37.
__global__ __launch_bounds__(256)
void final_kernel(const float* __restrict__ h, const float* __restrict__ mask,
                  const float* __restrict__ w12, const float* __restrict__ w13,
                  float* __restrict__ out)
{
    __shared__ float o1[256];
    const int co = threadIdx.x;
    const float m = (mask[0] > 0.f) ? 1.f : 0.f;
    float a = 0.f;
    for (int ci = 0; ci < 224; ++ci)
        a += h[ci] * w12[(size_t)(37 * 224 + ci) * 256 + co];
    o1[co] = a * m;
    __syncthreads();
    float b = 0.f;
    for (int ci = 0; ci < 256; ++ci)
        b += o1[ci] * w13[(size_t)(37 * 256 + ci) * 256 + co];
    out[co] = b * m;
}

static void pool_launch(const float* in, const float* mi, float* out, float* mo,
                        int S, int C, hipStream_t stream)
{
    const long long total = (long long)(S / 2) * (S / 2) * (S / 2) * C;
    long long grid = (total + 255) / 256;
    if (grid > 8192) grid = 8192;
    if (grid < 1) grid = 1;
    pool_kernel<<<(int)grid, 256, 0, stream>>>(in, mi, out, mo, S, C);
}

extern "C" void kernel_launch(void* const* d_in, const int* in_sizes, int n_in,
                              void* d_out, int out_size, void* d_ws, size_t ws_size,
                              hipStream_t stream)
{
    const float* feats = (const float*)d_in[0];
    const int*   coors = (const int*)d_in[1];
    const float* w[14];
    for (int i = 0; i < 14; ++i) w[i] = (const float*)d_in[3 + i];
    float* outp = (float*)d_out;

    constexpr size_t HBUF = (size_t)64 * 64 * 64 * 64;  // 16.78M floats
    float* hA = (float*)d_ws;
    float* hB = hA + HBUF;
    float* mA = hB + HBUF;
    float* mB = mA + (size_t)64 * 64 * 64;

    const int npts = in_sizes[0] / 3;

    hipMemsetAsync(hA, 0, (size_t)64 * 64 * 64 * 3 * sizeof(float), stream);
    hipMemsetAsync(mA, 0, (size_t)64 * 64 * 64 * sizeof(float), stream);
    scatter_kernel<<<(npts + 255) / 256, 256, 0, stream>>>(feats, coors, hA, mA, npts);

    // Level 0 (64^3)
    conv_kernel<3, 64, 64, 3, 4><<<dim3(64, 64), 256, 0, stream>>>(hA, w[0], mA, hB);
    conv_kernel<64, 64, 64, 8, 4><<<dim3(64, 64), 256, 0, stream>>>(hB, w[1], mA, hA);
    pool_launch(hA, mA, hB, mB, 64, 64, stream);
    // Level 1 (32^3)
    conv_kernel<64, 96, 32, 16, 2><<<dim3(32, 32), 192, 0, stream>>>(hB, w[2], mB, hA);
    conv_kernel<96, 96, 32, 16, 2><<<dim3(32, 32), 192, 0, stream>>>(hA, w[3], mB, hB);
    pool_launch(hB, mB, hA, mA, 32, 96, stream);
    // Level 2 (16^3)
    conv_kernel<96, 128, 16, 32, 2><<<dim3(16, 16), 256, 0, stream>>>(hA, w[4], mA, hB);
    conv_kernel<128, 128, 16, 32, 2><<<dim3(16, 16), 256, 0, stream>>>(hB, w[5], mA, hA);
    pool_launch(hA, mA, hB, mB, 16, 128, stream);
    // Level 3 (8^3)
    conv_kernel<128, 160, 8, 32, 1><<<dim3(8, 8), 160, 0, stream>>>(hB, w[6], mB, hA);
    conv_kernel<160, 160, 8, 32, 1><<<dim3(8, 8), 160, 0, stream>>>(hA, w[7], mB, hB);
    pool_launch(hB, mB, hA, mA, 8, 160, stream);
    // Level 4 (4^3)
    conv_kernel<160, 192, 4, 32, 1><<<dim3(4, 4), 192, 0, stream>>>(hA, w[8], mA, hB);
    conv_kernel<192, 192, 4, 32, 1><<<dim3(4, 4), 192, 0, stream>>>(hB, w[9], mA, hA);
    pool_launch(hA, mA, hB, mB, 4, 192, stream);
    // Level 5 (2^3)
    conv_kernel<192, 224, 2, 32, 1><<<dim3(2, 2), 224, 0, stream>>>(hB, w[10], mB, hA);
    conv_kernel<224, 224, 2, 32, 1><<<dim3(2, 2), 224, 0, stream>>>(hA, w[11], mB, hB);
    pool_launch(hB, mB, hA, mA, 2, 224, stream);
    // Final 1x1x1 convs (center tap only)
    final_kernel<<<1, 256, 0, stream>>>(hA, mA, w[12], w[13], outp);
}

// Round 2
// 9909.608 us; speedup vs baseline: 1.3232x; 1.3232x over previous
//
#include <hip/hip_runtime.h>
#include <hip/hip_bf16.h>
#include <cstdint>

typedef __attribute__((ext_vector_type(8))) short bf16x8;
typedef __attribute__((ext_vector_type(4))) float f32x4;

__device__ __forceinline__ unsigned short f2bf_hi(float v) {
    unsigned u = __float_as_uint(v);
    u = u + 0x7fffu + ((u >> 16) & 1u);
    return (unsigned short)(u >> 16);
}
__device__ __forceinline__ float bf2f(unsigned short h) {
    return __uint_as_float(((unsigned)h) << 16);
}

// ---------------------------------------------------------------------------
__global__ void scatter_kernel(const float* __restrict__ feats,
                               const int* __restrict__ coors,
                               float* __restrict__ dense,
                               float* __restrict__ mask, int n)
{
    int i = blockIdx.x * blockDim.x + threadIdx.x;
    if (i >= n) return;
    const int z = coors[i * 4 + 1];
    const int y = coors[i * 4 + 2];
    const int x = coors[i * 4 + 3];
    const size_t s = (size_t)((z * 64 + y) * 64 + x);
    dense[s * 3 + 0] = feats[i * 3 + 0];
    dense[s * 3 + 1] = feats[i * 3 + 1];
    dense[s * 3 + 2] = feats[i * 3 + 2];
    mask[s] = 1.f;
}

// fp32 -> bf16 hi/lo split (elementwise, vectorized x4)
__global__ void cvt_kernel(const float* __restrict__ in,
                           unsigned short* __restrict__ hi,
                           unsigned short* __restrict__ lo, int n4)
{
    const int stride = gridDim.x * blockDim.x;
    for (int i = blockIdx.x * blockDim.x + threadIdx.x; i < n4; i += stride) {
        float4 v = ((const float4*)in)[i];
        unsigned short h0 = f2bf_hi(v.x), h1 = f2bf_hi(v.y);
        unsigned short h2 = f2bf_hi(v.z), h3 = f2bf_hi(v.w);
        ((ushort4*)hi)[i] = make_ushort4(h0, h1, h2, h3);
        ((ushort4*)lo)[i] = make_ushort4(f2bf_hi(v.x - bf2f(h0)), f2bf_hi(v.y - bf2f(h1)),
                                         f2bf_hi(v.z - bf2f(h2)), f2bf_hi(v.w - bf2f(h3)));
    }
}

// weights [tap(75)][ci][co] fp32 -> hi/lo bf16 in MFMA layout [tap][ci/8][co][8]
__global__ void wprep_kernel(const float* __restrict__ w,
                             unsigned short* __restrict__ wh,
                             unsigned short* __restrict__ wl, int CI, int CO)
{
    const int total = 75 * CI * CO;
    const int stride = gridDim.x * blockDim.x;
    for (int i = blockIdx.x * blockDim.x + threadIdx.x; i < total; i += stride) {
        const int tap = i / (CI * CO);
        const int r = i - tap * CI * CO;
        const int ci = r / CO;
        const int co = r - ci * CO;
        const float v = w[i];
        const unsigned short h = f2bf_hi(v);
        const unsigned short l = f2bf_hi(v - bf2f(h));
        const size_t o = ((size_t)(tap * (CI / 8) + (ci >> 3)) * CO + co) * 8 + (ci & 7);
        wh[o] = h; wl[o] = l;
    }
}

// ---------------------------------------------------------------------------
// Split-bf16 MFMA implicit-GEMM conv, kernel (3,5,5), pad (1,2,2).
// One block per (z,y) output row (M = S). Per phase (kz,ky,kc): stage one
// padded input row (hi+lo, 32 channels) in LDS; 5 kx taps reuse it with
// shifted A-fragments. acc fp32 = ah*bh + al*bh + ah*bl.
template<int CIN, int COUT, int S, int WM, int WN, int NWAVES>
__global__ __launch_bounds__(NWAVES * 64)
void mfma_conv(const unsigned short* __restrict__ ah, const unsigned short* __restrict__ al,
               const unsigned short* __restrict__ wh, const unsigned short* __restrict__ wl,
               const float* __restrict__ mask, float* __restrict__ out)
{
    constexpr int SP = S + 4;
    constexpr int MF = S / 16;
    constexpr int NF = COUT / 16;
    constexpr int MG = MF / WM;
    constexpr int NG = NF / WN;
    static_assert(NWAVES == MG * NG, "wave mismatch");
    constexpr int NT = NWAVES * 64;
    constexpr int KC = CIN / 32;

    __shared__ unsigned short lds[2 * SP * 32];

    const int y = blockIdx.x, z = blockIdx.y;
    const int t = threadIdx.x;
    const int lane = t & 63;
    const int wave = t >> 6;
    const int waveM = wave % MG;
    const int waveN = wave / MG;
    const int col = lane & 15;
    const int ci8 = lane >> 4;

    f32x4 acc[WM][WN];
    const f32x4 vzero = {0.f, 0.f, 0.f, 0.f};
#pragma unroll
    for (int m = 0; m < WM; ++m)
#pragma unroll
        for (int n = 0; n < WN; ++n) acc[m][n] = vzero;

#pragma unroll 1
    for (int kzy = 0; kzy < 15; ++kzy) {
        const int kz = kzy / 5, ky = kzy - kz * 5;
        const int zz = z + kz - 1, yy = y + ky - 2;
        const bool rv = ((unsigned)zz < (unsigned)S) && ((unsigned)yy < (unsigned)S);
        const size_t rowbase = rv ? (size_t)((zz * S + yy) * S) * CIN : 0;
#pragma unroll 1
        for (int kc = 0; kc < KC; ++kc) {
            __syncthreads();
            constexpr int CH = SP * 4;   // 16B chunks per plane
#pragma unroll
            for (int c0 = 0; c0 < 2 * CH; c0 += NT) {
                const int c = c0 + t;
                if (c < 2 * CH) {
                    const int pl = (c >= CH) ? 1 : 0;
                    const int cc = c - pl * CH;
                    const int xi = (cc >> 2) - 2;
                    const int q = cc & 3;
                    uint4 v = {0u, 0u, 0u, 0u};
                    if (rv && (unsigned)xi < (unsigned)S) {
                        const unsigned short* src =
                            (pl ? al : ah) + rowbase + (size_t)xi * CIN + kc * 32 + q * 8;
                        v = *(const uint4*)src;
                    }
                    *(uint4*)(lds + c * 8) = v;
                }
            }
            __syncthreads();
#pragma unroll
            for (int kx = 0; kx < 5; ++kx) {
                const int tap = kzy * 5 + kx;
                bf16x8 bh[WN], bl[WN];
#pragma unroll
                for (int n = 0; n < WN; ++n) {
                    const int co = (waveN * WN + n) * 16 + col;
                    const size_t o = ((size_t)(tap * (CIN / 8) + kc * 4 + ci8) * COUT + co) * 8;
                    bh[n] = *(const bf16x8*)(wh + o);
                    bl[n] = *(const bf16x8*)(wl + o);
                }
#pragma unroll
                for (int m = 0; m < WM; ++m) {
                    const int x = (waveM * WM + m) * 16 + col + kx;
                    const unsigned short* ap = lds + x * 32 + ci8 * 8;
                    bf16x8 a_h = *(const bf16x8*)ap;
                    bf16x8 a_l = *(const bf16x8*)(ap + SP * 32);
#pragma unroll
                    for (int n = 0; n < WN; ++n) {
                        acc[m][n] = __builtin_amdgcn_mfma_f32_16x16x32_bf16(a_h, bh[n], acc[m][n], 0, 0, 0);
                        acc[m][n] = __builtin_amdgcn_mfma_f32_16x16x32_bf16(a_l, bh[n], acc[m][n], 0, 0, 0);
                        acc[m][n] = __builtin_amdgcn_mfma_f32_16x16x32_bf16(a_h, bl[n], acc[m][n], 0, 0, 0);
                    }
                }
            }
        }
    }

    const int rq = lane >> 4;
    const size_t vb = (size_t)(z * S + y) * S;
#pragma unroll
    for (int m = 0; m < WM; ++m) {
        const int xb = (waveM * WM + m) * 16 + rq * 4;
#pragma unroll
        for (int r = 0; r < 4; ++r) {
            const int x = xb + r;
            const float keep = (mask[vb + x] > 0.f) ? 1.f : 0.f;
#pragma unroll
            for (int n = 0; n < WN; ++n) {
                const int co = (waveN * WN + n) * 16 + col;
                out[(vb + x) * COUT + co] = acc[m][n][r] * keep;
            }
        }
    }
}

// ---------------------------------------------------------------------------
// fp32 vector conv (kept for CIN=3 first layer and small deep levels)
template<int CIN, int COUT, int S, int CIC, int G>
__global__ __launch_bounds__(COUT * G)
void conv_kernel(const float* __restrict__ in, const float* __restrict__ w,
                 const float* __restrict__ mask, float* __restrict__ out)
{
    constexpr int XT = S / G;
    constexpr int SP = S + 4;
    constexpr int NT = COUT * G;
    __shared__ float lds[15 * SP * CIC];

    const int y = blockIdx.x;
    const int z = blockIdx.y;
    const int t = threadIdx.x;
    const int co = t % COUT;
    const int xb = (t / COUT) * XT;

    float acc[XT];
#pragma unroll
    for (int i = 0; i < XT; ++i) acc[i] = 0.f;

    constexpr int NCHUNK = CIN / CIC;
#pragma unroll 1
    for (int cc = 0; cc < NCHUNK; ++cc) {
        __syncthreads();
        constexpr int TOTAL = 15 * SP * CIC;
        for (int idx = t; idx < TOTAL; idx += NT) {
            const int r   = idx / (SP * CIC);
            const int rem = idx - r * (SP * CIC);
            const int xx  = rem / CIC;
            const int ci  = rem - xx * CIC;
            const int kz = r / 5, ky = r - kz * 5;
            const int zz = z + kz - 1;
            const int yy = y + ky - 2;
            const int xi = xx - 2;
            float v = 0.f;
            if (zz >= 0 && zz < S && yy >= 0 && yy < S && xi >= 0 && xi < S)
                v = in[(size_t)((zz * S + yy) * S + xi) * CIN + cc * CIC + ci];
            lds[idx] = v;
        }
        __syncthreads();

#pragma unroll
        for (int kz = 0; kz < 3; ++kz)
#pragma unroll
        for (int ky = 0; ky < 5; ++ky) {
            const float* lrow = &lds[(kz * 5 + ky) * SP * CIC];
            const float* wrow = w + (size_t)((kz * 5 + ky) * 5) * CIN * COUT
                                  + (size_t)cc * CIC * COUT + co;
#pragma unroll 1
            for (int ci = 0; ci < CIC; ++ci) {
                float inv[XT + 4];
#pragma unroll
                for (int j = 0; j < XT + 4; ++j)
                    inv[j] = lrow[(xb + j) * CIC + ci];
                const float* wp = wrow + (size_t)ci * COUT;
#pragma unroll
                for (int kx = 0; kx < 5; ++kx) {
                    const float wv = wp[(size_t)kx * CIN * COUT];
#pragma unroll
                    for (int i = 0; i < XT; ++i)
                        acc[i] += inv[i + kx] * wv;
                }
            }
        }
    }

#pragma unroll
    for (int i = 0; i < XT; ++i) {
        const int x = xb + i;
        const float m = mask[(z * S + y) * S + x];
        out[(size_t)((z * S + y) * S + x) * COUT + co] = (m > 0.f) ? acc[i] : 0.f;
    }
}

// Sparse maxpool 2x2x2 with reference semantics.
__global__ void pool_kernel(const float* __restrict__ in, const float* __restrict__ mi,
                            float* __restrict__ out, float* __restrict__ mo,
                            int S, int C)
{
    const int So = S >> 1;
    const long long total = (long long)So * So * So * C;
    for (long long i = blockIdx.x * (long long)blockDim.x + threadIdx.x; i < total;
         i += (long long)gridDim.x * blockDim.x) {
        const int c = (int)(i % C);
        const long long s = i / C;
        const int xo = (int)(s % So);
        const int yo = (int)((s / So) % So);
        const int zo = (int)(s / ((long long)So * So));
        float best = -1e30f;
        float m2 = 0.f;
        for (int dz = 0; dz < 2; ++dz)
            for (int dy = 0; dy < 2; ++dy)
                for (int dx = 0; dx < 2; ++dx) {
                    const int zi = zo * 2 + dz, yi = yo * 2 + dy, xi = xo * 2 + dx;
                    const float m = mi[(zi * S + yi) * S + xi];
                    if (m > 0.f) {
                        m2 = 1.f;
                        best = fmaxf(best, in[(size_t)((zi * S + yi) * S + xi) * C + c]);
                    }
                }
        out[i] = (m2 > 0.f) ? best : 0.f;
        if (c == 0) mo[s] = m2;
    }
}

__global__ __launch_bounds__(256)
void final_kernel(const float* __restrict__ h, const float* __restrict__ mask,
                  const float* __restrict__ w12, const float* __restrict__ w13,
                  float* __restrict__ out)
{
    __shared__ float o1[256];
    const int co = threadIdx.x;
    const float m = (mask[0] > 0.f) ? 1.f : 0.f;
    float a = 0.f;
    for (int ci = 0; ci < 224; ++ci)
        a += h[ci] * w12[(size_t)(37 * 224 + ci) * 256 + co];
    o1[co] = a * m;
    __syncthreads();
    float b = 0.f;
    for (int ci = 0; ci < 256; ++ci)
        b += o1[ci] * w13[(size_t)(37 * 256 + ci) * 256 + co];
    out[co] = b * m;
}

static void pool_launch(const float* in, const float* mi, float* out, float* mo,
                        int S, int C, hipStream_t stream)
{
    const long long total = (long long)(S / 2) * (S / 2) * (S / 2) * C;
    long long grid = (total + 255) / 256;
    if (grid > 8192) grid = 8192;
    if (grid < 1) grid = 1;
    pool_kernel<<<(int)grid, 256, 0, stream>>>(in, mi, out, mo, S, C);
}

// weight-pool element offsets (layers: L0c2, L1c1, L1c2, L2c1, L2c2)
#define OFF0 0
#define OFF1 307200
#define OFF2 768000
#define OFF3 1459200
#define OFF4 2380800

extern "C" void kernel_launch(void* const* d_in, const int* in_sizes, int n_in,
                              void* d_out, int out_size, void* d_ws, size_t ws_size,
                              hipStream_t stream)
{
    const float* feats = (const float*)d_in[0];
    const int*   coors = (const int*)d_in[1];
    const float* w[14];
    for (int i = 0; i < 14; ++i) w[i] = (const float*)d_in[3 + i];
    float* outp = (float*)d_out;

    float* hA = (float*)d_ws;
    float* hB = hA + 16777216;
    float* mA = hB + 16777216;
    float* mB = mA + 262144;
    unsigned short* ah = (unsigned short*)(mB + 262144);
    unsigned short* al = ah + 16777216;
    unsigned short* wh = al + 16777216;
    unsigned short* wl = wh + 3609600;

    const int npts = in_sizes[0] / 3;

    // weight prep for the 5 MFMA layers (independent of activations)
    wprep_kernel<<<256, 256, 0, stream>>>(w[1], wh + OFF0, wl + OFF0, 64, 64);
    wprep_kernel<<<256, 256, 0, stream>>>(w[2], wh + OFF1, wl + OFF1, 64, 96);
    wprep_kernel<<<256, 256, 0, stream>>>(w[3], wh + OFF2, wl + OFF2, 96, 96);
    wprep_kernel<<<256, 256, 0, stream>>>(w[4], wh + OFF3, wl + OFF3, 96, 128);
    wprep_kernel<<<256, 256, 0, stream>>>(w[5], wh + OFF4, wl + OFF4, 128, 128);

    hipMemsetAsync(hA, 0, (size_t)262144 * 3 * sizeof(float), stream);
    hipMemsetAsync(mA, 0, (size_t)262144 * sizeof(float), stream);
    scatter_kernel<<<(npts + 255) / 256, 256, 0, stream>>>(feats, coors, hA, mA, npts);

    // Level 0 (64^3)
    conv_kernel<3, 64, 64, 3, 4><<<dim3(64, 64), 256, 0, stream>>>(hA, w[0], mA, hB);
    cvt_kernel<<<2048, 256, 0, stream>>>(hB, ah, al, 16777216 / 4);
    mfma_conv<64, 64, 64, 2, 4, 2><<<dim3(64, 64), 128, 0, stream>>>(ah, al, wh + OFF0, wl + OFF0, mA, hA);
    pool_launch(hA, mA, hB, mB, 64, 64, stream);
    // Level 1 (32^3)
    cvt_kernel<<<2048, 256, 0, stream>>>(hB, ah, al, 2097152 / 4);
    mfma_conv<64, 96, 32, 2, 3, 2><<<dim3(32, 32), 128, 0, stream>>>(ah, al, wh + OFF1, wl + OFF1, mB, hA);
    cvt_kernel<<<2048, 256, 0, stream>>>(hA, ah, al, 3145728 / 4);
    mfma_conv<96, 96, 32, 2, 3, 2><<<dim3(32, 32), 128, 0, stream>>>(ah, al, wh + OFF2, wl + OFF2, mB, hB);
    pool_launch(hB, mB, hA, mA, 32, 96, stream);
    // Level 2 (16^3)
    cvt_kernel<<<1024, 256, 0, stream>>>(hA, ah, al, 393216 / 4);
    mfma_conv<96, 128, 16, 1, 4, 2><<<dim3(16, 16), 128, 0, stream>>>(ah, al, wh + OFF3, wl + OFF3, mA, hB);
    cvt_kernel<<<1024, 256, 0, stream>>>(hB, ah, al, 524288 / 4);
    mfma_conv<128, 128, 16, 1, 4, 2><<<dim3(16, 16), 128, 0, stream>>>(ah, al, wh + OFF4, wl + OFF4, mA, hA);
    pool_launch(hA, mA, hB, mB, 16, 128, stream);
    // Level 3 (8^3)
    conv_kernel<128, 160, 8, 32, 1><<<dim3(8, 8), 160, 0, stream>>>(hB, w[6], mB, hA);
    conv_kernel<160, 160, 8, 32, 1><<<dim3(8, 8), 160, 0, stream>>>(hA, w[7], mB, hB);
    pool_launch(hB, mB, hA, mA, 8, 160, stream);
    // Level 4 (4^3)
    conv_kernel<160, 192, 4, 32, 1><<<dim3(4, 4), 192, 0, stream>>>(hA, w[8], mA, hB);
    conv_kernel<192, 192, 4, 32, 1><<<dim3(4, 4), 192, 0, stream>>>(hB, w[9], mA, hA);
    pool_launch(hA, mA, hB, mB, 4, 192, stream);
    // Level 5 (2^3)
    conv_kernel<192, 224, 2, 32, 1><<<dim3(2, 2), 224, 0, stream>>>(hB, w[10], mB, hA);
    conv_kernel<224, 224, 2, 32, 1><<<dim3(2, 2), 224, 0, stream>>>(hA, w[11], mB, hB);
    pool_launch(hB, mB, hA, mA, 2, 224, stream);
    // Final 1x1x1 convs (center tap only)
    final_kernel<<<1, 256, 0, stream>>>(hA, mA, w[12], w[13], outp);
}

// Round 3
// 2673.420 us; speedup vs baseline: 4.9046x; 3.7067x over previous
//
#include <hip/hip_runtime.h>
#include <hip/hip_bf16.h>
#include <cstdint>

typedef __attribute__((ext_vector_type(8))) short bf16x8;
typedef __attribute__((ext_vector_type(4))) float f32x4;

__device__ __forceinline__ unsigned short f2bf_hi(float v) {
    unsigned u = __float_as_uint(v);
    u = u + 0x7fffu + ((u >> 16) & 1u);
    return (unsigned short)(u >> 16);
}
__device__ __forceinline__ float bf2f(unsigned short h) {
    return __uint_as_float(((unsigned)h) << 16);
}

// ---------------------------------------------------------------------------
__global__ void scatter_kernel(const float* __restrict__ feats,
                               const int* __restrict__ coors,
                               float* __restrict__ dense,
                               float* __restrict__ mask, int n)
{
    int i = blockIdx.x * blockDim.x + threadIdx.x;
    if (i >= n) return;
    const int z = coors[i * 4 + 1];
    const int y = coors[i * 4 + 2];
    const int x = coors[i * 4 + 3];
    const size_t s = (size_t)((z * 64 + y) * 64 + x);
    dense[s * 3 + 0] = feats[i * 3 + 0];
    dense[s * 3 + 1] = feats[i * 3 + 1];
    dense[s * 3 + 2] = feats[i * 3 + 2];
    mask[s] = 1.f;
}

// fp32 -> bf16 hi/lo split (elementwise, vectorized x4)
__global__ void cvt_kernel(const float* __restrict__ in,
                           unsigned short* __restrict__ hi,
                           unsigned short* __restrict__ lo, int n4)
{
    const int stride = gridDim.x * blockDim.x;
    for (int i = blockIdx.x * blockDim.x + threadIdx.x; i < n4; i += stride) {
        float4 v = ((const float4*)in)[i];
        unsigned short h0 = f2bf_hi(v.x), h1 = f2bf_hi(v.y);
        unsigned short h2 = f2bf_hi(v.z), h3 = f2bf_hi(v.w);
        ((ushort4*)hi)[i] = make_ushort4(h0, h1, h2, h3);
        ((ushort4*)lo)[i] = make_ushort4(f2bf_hi(v.x - bf2f(h0)), f2bf_hi(v.y - bf2f(h1)),
                                         f2bf_hi(v.z - bf2f(h2)), f2bf_hi(v.w - bf2f(h3)));
    }
}

// weights [tap(75)][ci][co] fp32 -> hi/lo bf16 in MFMA layout [tap][ci/8][co][8]
__global__ void wprep_kernel(const float* __restrict__ w,
                             unsigned short* __restrict__ wh,
                             unsigned short* __restrict__ wl, int CI, int CO)
{
    const int total = 75 * CI * CO;
    const int stride = gridDim.x * blockDim.x;
    for (int i = blockIdx.x * blockDim.x + threadIdx.x; i < total; i += stride) {
        const int tap = i / (CI * CO);
        const int r = i - tap * CI * CO;
        const int ci = r / CO;
        const int co = r - ci * CO;
        const float v = w[i];
        const unsigned short h = f2bf_hi(v);
        const unsigned short l = f2bf_hi(v - bf2f(h));
        const size_t o = ((size_t)(tap * (CI / 8) + (ci >> 3)) * CO + co) * 8 + (ci & 7);
        wh[o] = h; wl[o] = l;
    }
}

// ---------------------------------------------------------------------------
// Split-bf16 MFMA implicit-GEMM conv, kernel (3,5,5), pad (1,2,2).
template<int CIN, int COUT, int S, int WM, int WN, int NWAVES>
__global__ __launch_bounds__(NWAVES * 64)
void mfma_conv(const unsigned short* __restrict__ ah, const unsigned short* __restrict__ al,
               const unsigned short* __restrict__ wh, const unsigned short* __restrict__ wl,
               const float* __restrict__ mask, float* __restrict__ out)
{
    constexpr int SP = S + 4;
    constexpr int MF = S / 16;
    constexpr int NF = COUT / 16;
    constexpr int MG = MF / WM;
    constexpr int NG = NF / WN;
    static_assert(NWAVES == MG * NG, "wave mismatch");
    constexpr int NT = NWAVES * 64;
    constexpr int KC = CIN / 32;

    __shared__ unsigned short lds[2 * SP * 32];

    const int y = blockIdx.x, z = blockIdx.y;
    const int t = threadIdx.x;
    const int lane = t & 63;
    const int wave = t >> 6;
    const int waveM = wave % MG;
    const int waveN = wave / MG;
    const int col = lane & 15;
    const int ci8 = lane >> 4;

    f32x4 acc[WM][WN];
    const f32x4 vzero = {0.f, 0.f, 0.f, 0.f};
#pragma unroll
    for (int m = 0; m < WM; ++m)
#pragma unroll
        for (int n = 0; n < WN; ++n) acc[m][n] = vzero;

#pragma unroll 1
    for (int kzy = 0; kzy < 15; ++kzy) {
        const int kz = kzy / 5, ky = kzy - kz * 5;
        const int zz = z + kz - 1, yy = y + ky - 2;
        const bool rv = ((unsigned)zz < (unsigned)S) && ((unsigned)yy < (unsigned)S);
        const size_t rowbase = rv ? (size_t)((zz * S + yy) * S) * CIN : 0;
#pragma unroll 1
        for (int kc = 0; kc < KC; ++kc) {
            __syncthreads();
            constexpr int CH = SP * 4;   // 16B chunks per plane
#pragma unroll
            for (int c0 = 0; c0 < 2 * CH; c0 += NT) {
                const int c = c0 + t;
                if (c < 2 * CH) {
                    const int pl = (c >= CH) ? 1 : 0;
                    const int cc = c - pl * CH;
                    const int xi = (cc >> 2) - 2;
                    const int q = cc & 3;
                    uint4 v = {0u, 0u, 0u, 0u};
                    if (rv && (unsigned)xi < (unsigned)S) {
                        const unsigned short* src =
                            (pl ? al : ah) + rowbase + (size_t)xi * CIN + kc * 32 + q * 8;
                        v = *(const uint4*)src;
                    }
                    *(uint4*)(lds + c * 8) = v;
                }
            }
            __syncthreads();
#pragma unroll
            for (int kx = 0; kx < 5; ++kx) {
                const int tap = kzy * 5 + kx;
                bf16x8 bh[WN], bl[WN];
#pragma unroll
                for (int n = 0; n < WN; ++n) {
                    const int co = (waveN * WN + n) * 16 + col;
                    const size_t o = ((size_t)(tap * (CIN / 8) + kc * 4 + ci8) * COUT + co) * 8;
                    bh[n] = *(const bf16x8*)(wh + o);
                    bl[n] = *(const bf16x8*)(wl + o);
                }
#pragma unroll
                for (int m = 0; m < WM; ++m) {
                    const int x = (waveM * WM + m) * 16 + col + kx;
                    const unsigned short* ap = lds + x * 32 + ci8 * 8;
                    bf16x8 a_h = *(const bf16x8*)ap;
                    bf16x8 a_l = *(const bf16x8*)(ap + SP * 32);
#pragma unroll
                    for (int n = 0; n < WN; ++n) {
                        acc[m][n] = __builtin_amdgcn_mfma_f32_16x16x32_bf16(a_h, bh[n], acc[m][n], 0, 0, 0);
                        acc[m][n] = __builtin_amdgcn_mfma_f32_16x16x32_bf16(a_l, bh[n], acc[m][n], 0, 0, 0);
                        acc[m][n] = __builtin_amdgcn_mfma_f32_16x16x32_bf16(a_h, bl[n], acc[m][n], 0, 0, 0);
                    }
                }
            }
        }
    }

    const int rq = lane >> 4;
    const size_t vb = (size_t)(z * S + y) * S;
#pragma unroll
    for (int m = 0; m < WM; ++m) {
        const int xb = (waveM * WM + m) * 16 + rq * 4;
#pragma unroll
        for (int r = 0; r < 4; ++r) {
            const int x = xb + r;
            const float keep = (mask[vb + x] > 0.f) ? 1.f : 0.f;
#pragma unroll
            for (int n = 0; n < WN; ++n) {
                const int co = (waveN * WN + n) * 16 + col;
                out[(vb + x) * COUT + co] = acc[m][n][r] * keep;
            }
        }
    }
}

// ---------------------------------------------------------------------------
// Deep-level conv: one block per OUTPUT VOXEL (grid S^3), threads = COUT.
// Per valid tap: stage in[zz,yy,xi,:] (CIN floats) to LDS cooperatively,
// then each thread co accumulates CIN FMAs; weight loads coalesced over co.
template<int CIN, int COUT, int S>
__global__ __launch_bounds__(COUT)
void dconv_kernel(const float* __restrict__ in, const float* __restrict__ w,
                  const float* __restrict__ mask, float* __restrict__ out)
{
    __shared__ float buf[CIN];
    const int x = blockIdx.x, y = blockIdx.y, z = blockIdx.z;
    const int co = threadIdx.x;

    float a0 = 0.f, a1 = 0.f, a2 = 0.f, a3 = 0.f;

#pragma unroll 1
    for (int kz = 0; kz < 3; ++kz) {
        const int zz = z + kz - 1;
        if ((unsigned)zz >= (unsigned)S) continue;
#pragma unroll 1
        for (int ky = 0; ky < 5; ++ky) {
            const int yy = y + ky - 2;
            if ((unsigned)yy >= (unsigned)S) continue;
#pragma unroll 1
            for (int kx = 0; kx < 5; ++kx) {
                const int xi = x + kx - 2;
                if ((unsigned)xi >= (unsigned)S) continue;
                const int tap = (kz * 5 + ky) * 5 + kx;
                __syncthreads();
                {
                    const float* src = in + (size_t)((zz * S + yy) * S + xi) * CIN;
                    for (int ci = co; ci < CIN; ci += COUT) buf[ci] = src[ci];
                }
                __syncthreads();
                const float* wp = w + (size_t)tap * CIN * COUT + co;
#pragma unroll 4
                for (int ci = 0; ci < CIN; ci += 4) {
                    a0 += buf[ci + 0] * wp[(size_t)(ci + 0) * COUT];
                    a1 += buf[ci + 1] * wp[(size_t)(ci + 1) * COUT];
                    a2 += buf[ci + 2] * wp[(size_t)(ci + 2) * COUT];
                    a3 += buf[ci + 3] * wp[(size_t)(ci + 3) * COUT];
                }
            }
        }
    }

    const size_t vox = (size_t)(z * S + y) * S + x;
    const float keep = (mask[vox] > 0.f) ? 1.f : 0.f;
    out[vox * COUT + co] = (a0 + a1 + a2 + a3) * keep;
}

// ---------------------------------------------------------------------------
// fp32 vector conv (kept for CIN=3 first layer)
template<int CIN, int COUT, int S, int CIC, int G>
__global__ __launch_bounds__(COUT * G)
void conv_kernel(const float* __restrict__ in, const float* __restrict__ w,
                 const float* __restrict__ mask, float* __restrict__ out)
{
    constexpr int XT = S / G;
    constexpr int SP = S + 4;
    constexpr int NT = COUT * G;
    __shared__ float lds[15 * SP * CIC];

    const int y = blockIdx.x;
    const int z = blockIdx.y;
    const int t = threadIdx.x;
    const int co = t % COUT;
    const int xb = (t / COUT) * XT;

    float acc[XT];
#pragma unroll
    for (int i = 0; i < XT; ++i) acc[i] = 0.f;

    constexpr int NCHUNK = CIN / CIC;
#pragma unroll 1
    for (int cc = 0; cc < NCHUNK; ++cc) {
        __syncthreads();
        constexpr int TOTAL = 15 * SP * CIC;
        for (int idx = t; idx < TOTAL; idx += NT) {
            const int r   = idx / (SP * CIC);
            const int rem = idx - r * (SP * CIC);
            const int xx  = rem / CIC;
            const int ci  = rem - xx * CIC;
            const int kz = r / 5, ky = r - kz * 5;
            const int zz = z + kz - 1;
            const int yy = y + ky - 2;
            const int xi = xx - 2;
            float v = 0.f;
            if (zz >= 0 && zz < S && yy >= 0 && yy < S && xi >= 0 && xi < S)
                v = in[(size_t)((zz * S + yy) * S + xi) * CIN + cc * CIC + ci];
            lds[idx] = v;
        }
        __syncthreads();

#pragma unroll
        for (int kz = 0; kz < 3; ++kz)
#pragma unroll
        for (int ky = 0; ky < 5; ++ky) {
            const float* lrow = &lds[(kz * 5 + ky) * SP * CIC];
            const float* wrow = w + (size_t)((kz * 5 + ky) * 5) * CIN * COUT
                                  + (size_t)cc * CIC * COUT + co;
#pragma unroll 1
            for (int ci = 0; ci < CIC; ++ci) {
                float inv[XT + 4];
#pragma unroll
                for (int j = 0; j < XT + 4; ++j)
                    inv[j] = lrow[(xb + j) * CIC + ci];
                const float* wp = wrow + (size_t)ci * COUT;
#pragma unroll
                for (int kx = 0; kx < 5; ++kx) {
                    const float wv = wp[(size_t)kx * CIN * COUT];
#pragma unroll
                    for (int i = 0; i < XT; ++i)
                        acc[i] += inv[i + kx] * wv;
                }
            }
        }
    }

#pragma unroll
    for (int i = 0; i < XT; ++i) {
        const int x = xb + i;
        const float m = mask[(z * S + y) * S + x];
        out[(size_t)((z * S + y) * S + x) * COUT + co] = (m > 0.f) ? acc[i] : 0.f;
    }
}

// Sparse maxpool 2x2x2 with reference semantics.
__global__ void pool_kernel(const float* __restrict__ in, const float* __restrict__ mi,
                            float* __restrict__ out, float* __restrict__ mo,
                            int S, int C)
{
    const int So = S >> 1;
    const long long total = (long long)So * So * So * C;
    for (long long i = blockIdx.x * (long long)blockDim.x + threadIdx.x; i < total;
         i += (long long)gridDim.x * blockDim.x) {
        const int c = (int)(i % C);
        const long long s = i / C;
        const int xo = (int)(s % So);
        const int yo = (int)((s / So) % So);
        const int zo = (int)(s / ((long long)So * So));
        float best = -1e30f;
        float m2 = 0.f;
        for (int dz = 0; dz < 2; ++dz)
            for (int dy = 0; dy < 2; ++dy)
                for (int dx = 0; dx < 2; ++dx) {
                    const int zi = zo * 2 + dz, yi = yo * 2 + dy, xi = xo * 2 + dx;
                    const float m = mi[(zi * S + yi) * S + xi];
                    if (m > 0.f) {
                        m2 = 1.f;
                        best = fmaxf(best, in[(size_t)((zi * S + yi) * S + xi) * C + c]);
                    }
                }
        out[i] = (m2 > 0.f) ? best : 0.f;
        if (c == 0) mo[s] = m2;
    }
}

__global__ __launch_bounds__(256)
void final_kernel(const float* __restrict__ h, const float* __restrict__ mask,
                  const float* __restrict__ w12, const float* __restrict__ w13,
                  float* __restrict__ out)
{
    __shared__ float o1[256];
    const int co = threadIdx.x;
    const float m = (mask[0] > 0.f) ? 1.f : 0.f;
    float a = 0.f;
    for (int ci = 0; ci < 224; ++ci)
        a += h[ci] * w12[(size_t)(37 * 224 + ci) * 256 + co];
    o1[co] = a * m;
    __syncthreads();
    float b = 0.f;
    for (int ci = 0; ci < 256; ++ci)
        b += o1[ci] * w13[(size_t)(37 * 256 + ci) * 256 + co];
    out[co] = b * m;
}

static void pool_launch(const float* in, const float* mi, float* out, float* mo,
                        int S, int C, hipStream_t stream)
{
    const long long total = (long long)(S / 2) * (S / 2) * (S / 2) * C;
    long long grid = (total + 255) / 256;
    if (grid > 8192) grid = 8192;
    if (grid < 1) grid = 1;
    pool_kernel<<<(int)grid, 256, 0, stream>>>(in, mi, out, mo, S, C);
}

// weight-pool element offsets (layers: L0c2, L1c1, L1c2, L2c1, L2c2)
#define OFF0 0
#define OFF1 307200
#define OFF2 768000
#define OFF3 1459200
#define OFF4 2380800

extern "C" void kernel_launch(void* const* d_in, const int* in_sizes, int n_in,
                              void* d_out, int out_size, void* d_ws, size_t ws_size,
                              hipStream_t stream)
{
    const float* feats = (const float*)d_in[0];
    const int*   coors = (const int*)d_in[1];
    const float* w[14];
    for (int i = 0; i < 14; ++i) w[i] = (const float*)d_in[3 + i];
    float* outp = (float*)d_out;

    float* hA = (float*)d_ws;
    float* hB = hA + 16777216;
    float* mA = hB + 16777216;
    float* mB = mA + 262144;
    unsigned short* ah = (unsigned short*)(mB + 262144);
    unsigned short* al = ah + 16777216;
    unsigned short* wh = al + 16777216;
    unsigned short* wl = wh + 3609600;

    const int npts = in_sizes[0] / 3;

    // weight prep for the 5 MFMA layers (independent of activations)
    wprep_kernel<<<256, 256, 0, stream>>>(w[1], wh + OFF0, wl + OFF0, 64, 64);
    wprep_kernel<<<256, 256, 0, stream>>>(w[2], wh + OFF1, wl + OFF1, 64, 96);
    wprep_kernel<<<256, 256, 0, stream>>>(w[3], wh + OFF2, wl + OFF2, 96, 96);
    wprep_kernel<<<256, 256, 0, stream>>>(w[4], wh + OFF3, wl + OFF3, 96, 128);
    wprep_kernel<<<256, 256, 0, stream>>>(w[5], wh + OFF4, wl + OFF4, 128, 128);

    hipMemsetAsync(hA, 0, (size_t)262144 * 3 * sizeof(float), stream);
    hipMemsetAsync(mA, 0, (size_t)262144 * sizeof(float), stream);
    scatter_kernel<<<(npts + 255) / 256, 256, 0, stream>>>(feats, coors, hA, mA, npts);

    // Level 0 (64^3)
    conv_kernel<3, 64, 64, 3, 4><<<dim3(64, 64), 256, 0, stream>>>(hA, w[0], mA, hB);
    cvt_kernel<<<2048, 256, 0, stream>>>(hB, ah, al, 16777216 / 4);
    mfma_conv<64, 64, 64, 2, 4, 2><<<dim3(64, 64), 128, 0, stream>>>(ah, al, wh + OFF0, wl + OFF0, mA, hA);
    pool_launch(hA, mA, hB, mB, 64, 64, stream);
    // Level 1 (32^3)
    cvt_kernel<<<2048, 256, 0, stream>>>(hB, ah, al, 2097152 / 4);
    mfma_conv<64, 96, 32, 2, 3, 2><<<dim3(32, 32), 128, 0, stream>>>(ah, al, wh + OFF1, wl + OFF1, mB, hA);
    cvt_kernel<<<2048, 256, 0, stream>>>(hA, ah, al, 3145728 / 4);
    mfma_conv<96, 96, 32, 2, 3, 2><<<dim3(32, 32), 128, 0, stream>>>(ah, al, wh + OFF2, wl + OFF2, mB, hB);
    pool_launch(hB, mB, hA, mA, 32, 96, stream);
    // Level 2 (16^3)
    cvt_kernel<<<1024, 256, 0, stream>>>(hA, ah, al, 393216 / 4);
    mfma_conv<96, 128, 16, 1, 4, 2><<<dim3(16, 16), 128, 0, stream>>>(ah, al, wh + OFF3, wl + OFF3, mA, hB);
    cvt_kernel<<<1024, 256, 0, stream>>>(hB, ah, al, 524288 / 4);
    mfma_conv<128, 128, 16, 1, 4, 2><<<dim3(16, 16), 128, 0, stream>>>(ah, al, wh + OFF4, wl + OFF4, mA, hA);
    pool_launch(hA, mA, hB, mB, 16, 128, stream);
    // Level 3 (8^3) — voxel-parallel deep conv
    dconv_kernel<128, 160, 8><<<dim3(8, 8, 8), 160, 0, stream>>>(hB, w[6], mB, hA);
    dconv_kernel<160, 160, 8><<<dim3(8, 8, 8), 160, 0, stream>>>(hA, w[7], mB, hB);
    pool_launch(hB, mB, hA, mA, 8, 160, stream);
    // Level 4 (4^3)
    dconv_kernel<160, 192, 4><<<dim3(4, 4, 4), 192, 0, stream>>>(hA, w[8], mA, hB);
    dconv_kernel<192, 192, 4><<<dim3(4, 4, 4), 192, 0, stream>>>(hB, w[9], mA, hA);
    pool_launch(hA, mA, hB, mB, 4, 192, stream);
    // Level 5 (2^3)
    dconv_kernel<192, 224, 2><<<dim3(2, 2, 2), 224, 0, stream>>>(hB, w[10], mB, hA);
    dconv_kernel<224, 224, 2><<<dim3(2, 2, 2), 224, 0, stream>>>(hA, w[11], mB, hB);
    pool_launch(hB, mB, hA, mA, 2, 224, stream);
    // Final 1x1x1 convs (center tap only)
    final_kernel<<<1, 256, 0, stream>>>(hA, mA, w[12], w[13], outp);
}

// Round 4
// 1861.228 us; speedup vs baseline: 7.0448x; 1.4364x over previous
//
#include <hip/hip_runtime.h>
#include <hip/hip_bf16.h>
#include <cstdint>

typedef __attribute__((ext_vector_type(8))) short bf16x8;
typedef __attribute__((ext_vector_type(4))) float f32x4;

__device__ __forceinline__ unsigned short f2bf_hi(float v) {
    unsigned u = __float_as_uint(v);
    u = u + 0x7fffu + ((u >> 16) & 1u);
    return (unsigned short)(u >> 16);
}
__device__ __forceinline__ float bf2f(unsigned short h) {
    return __uint_as_float(((unsigned)h) << 16);
}

// ---------------------------------------------------------------------------
__global__ void scatter_kernel(const float* __restrict__ feats,
                               const int* __restrict__ coors,
                               float* __restrict__ dense,
                               float* __restrict__ mask, int n)
{
    int i = blockIdx.x * blockDim.x + threadIdx.x;
    if (i >= n) return;
    const int z = coors[i * 4 + 1];
    const int y = coors[i * 4 + 2];
    const int x = coors[i * 4 + 3];
    const size_t s = (size_t)((z * 64 + y) * 64 + x);
    dense[s * 3 + 0] = feats[i * 3 + 0];
    dense[s * 3 + 1] = feats[i * 3 + 1];
    dense[s * 3 + 2] = feats[i * 3 + 2];
    mask[s] = 1.f;
}

// weights [tap(75)][ci][co] fp32 -> hi/lo bf16 in MFMA layout [tap][ci/8][co][8]
__global__ void wprep_kernel(const float* __restrict__ w,
                             unsigned short* __restrict__ wh,
                             unsigned short* __restrict__ wl, int CI, int CO)
{
    const int total = 75 * CI * CO;
    const int stride = gridDim.x * blockDim.x;
    for (int i = blockIdx.x * blockDim.x + threadIdx.x; i < total; i += stride) {
        const int tap = i / (CI * CO);
        const int r = i - tap * CI * CO;
        const int ci = r / CO;
        const int co = r - ci * CO;
        const float v = w[i];
        const unsigned short h = f2bf_hi(v);
        const unsigned short l = f2bf_hi(v - bf2f(h));
        const size_t o = ((size_t)(tap * (CI / 8) + (ci >> 3)) * CO + co) * 8 + (ci & 7);
        wh[o] = h; wl[o] = l;
    }
}

// ---------------------------------------------------------------------------
// L0 conv1: CIN=3, COUT=64, S=64. Planar LDS [row][ci][x], broadcast reads,
// fused bf16 hi/lo output. One block per (z,y) output row, 256 threads.
__global__ __launch_bounds__(256)
void conv1_kernel(const float* __restrict__ in, const float* __restrict__ w,
                  const float* __restrict__ mask,
                  unsigned short* __restrict__ oh, unsigned short* __restrict__ ol)
{
    constexpr int S = 64, SP = 68;
    __shared__ float lds[15][3][SP];

    const int bid = blockIdx.y * S + blockIdx.x;
    const int wg = (bid & 7) * (S * S / 8) + (bid >> 3);   // XCD-chunked
    const int y = wg & 63, z = wg >> 6;
    const int t = threadIdx.x;

    for (int idx = t; idx < 15 * 3 * SP; idx += 256) {
        const int r = idx / (3 * SP);
        const int rem = idx - r * 3 * SP;
        const int ci = rem / SP;
        const int x = rem - ci * SP;
        const int kz = r / 5, ky = r - kz * 5;
        const int zz = z + kz - 1, yy = y + ky - 2, xi = x - 2;
        float v = 0.f;
        if ((unsigned)zz < (unsigned)S && (unsigned)yy < (unsigned)S && (unsigned)xi < (unsigned)S)
            v = in[(size_t)((zz * S + yy) * S + xi) * 3 + ci];
        lds[r][ci][x] = v;
    }
    __syncthreads();

    const int co = t & 63, xs = t >> 6;
    float acc[16];
#pragma unroll
    for (int i = 0; i < 16; ++i) acc[i] = 0.f;

#pragma unroll 1
    for (int r = 0; r < 15; ++r) {
#pragma unroll
        for (int ci = 0; ci < 3; ++ci) {
            float inv[20];
#pragma unroll
            for (int j = 0; j < 5; ++j)
                *(float4*)&inv[j * 4] = *(const float4*)&lds[r][ci][xs * 16 + j * 4];
            const float* wp = w + (size_t)(r * 15 + ci) * 64 + co;
#pragma unroll
            for (int kx = 0; kx < 5; ++kx) {
                const float wv = wp[kx * 192];
#pragma unroll
                for (int i = 0; i < 16; ++i) acc[i] += inv[i + kx] * wv;
            }
        }
    }

    const size_t vb = (size_t)(z * S + y) * S;
#pragma unroll
    for (int i = 0; i < 16; ++i) {
        const int x = xs * 16 + i;
        const float keep = (mask[vb + x] > 0.f) ? 1.f : 0.f;
        const float v = acc[i] * keep;
        const unsigned short h = f2bf_hi(v);
        const unsigned short l = f2bf_hi(v - bf2f(h));
        oh[(vb + x) * 64 + co] = h;
        ol[(vb + x) * 64 + co] = l;
    }
}

// ---------------------------------------------------------------------------
// Split-bf16 MFMA implicit-GEMM conv v2: full-CIN rows (15 phases),
// reg-staged pipeline (T14), XOR-swizzled LDS (T2), XCD block swizzle (T1),
// setprio around MFMA, fused output mode (0 = fp32, 1 = bf16 hi/lo).
template<int CIN, int COUT, int S, int WM, int WN, int MG, int NG, int OMODE>
__global__ __launch_bounds__(MG * NG * 64)
void mfma_conv2(const unsigned short* __restrict__ ah, const unsigned short* __restrict__ al,
                const unsigned short* __restrict__ wh, const unsigned short* __restrict__ wl,
                const float* __restrict__ mask, float* __restrict__ outf,
                unsigned short* __restrict__ oh, unsigned short* __restrict__ ol)
{
    constexpr int SP = S + 4;
    constexpr int KC = CIN / 32;
    constexpr int KC4 = KC * 4;                 // logical 16B chunks per x per plane
    constexpr int RS = (KC4 <= 8) ? 8 : 16;     // padded chunks per x (pow2)
    constexpr int PLANE = SP * RS;              // chunks per plane
    constexpr int NL = SP * KC4;                // logical chunks per plane
    constexpr int NT = MG * NG * 64;
    constexpr int NLOG = 2 * NL;
    constexpr int SREG = (NLOG + NT - 1) / NT;
    static_assert(S / 16 == WM * MG && COUT / 16 == WN * NG, "geometry");

    __shared__ unsigned short lds[2 * PLANE * 8];

    const int bid = blockIdx.y * S + blockIdx.x;
    const int wg = (bid & 7) * (S * S / 8) + (bid >> 3);
    const int y = wg % S, z = wg / S;

    const int t = threadIdx.x;
    const int lane = t & 63;
    const int wave = t >> 6;
    const int waveM = wave % MG;
    const int waveN = wave / MG;
    const int col = lane & 15;
    const int ci8 = lane >> 4;

    f32x4 acc[WM][WN];
    const f32x4 vzero = {0.f, 0.f, 0.f, 0.f};
#pragma unroll
    for (int m = 0; m < WM; ++m)
#pragma unroll
        for (int n = 0; n < WN; ++n) acc[m][n] = vzero;

    uint4 reg[SREG];

    // prefetch lambda: fill reg[] for row kzy
    auto issue = [&](int kzy) {
        const int kz = kzy / 5, ky = kzy - kz * 5;
        const int zz = z + kz - 1, yy = y + ky - 2;
        const bool rv = ((unsigned)zz < (unsigned)S) && ((unsigned)yy < (unsigned)S);
        const size_t rowbase = rv ? (size_t)((zz * S + yy) * S) * CIN : 0;
#pragma unroll
        for (int i = 0; i < SREG; ++i) {
            const int L = i * NT + t;
            uint4 v = {0u, 0u, 0u, 0u};
            if (L < NLOG) {
                const int pl = (L >= NL) ? 1 : 0;
                const int l2 = L - pl * NL;
                const int x = l2 / KC4;
                const int c3 = l2 - x * KC4;
                const int xi = x - 2;
                if (rv && (unsigned)xi < (unsigned)S) {
                    const unsigned short* src = (pl ? al : ah) + rowbase + (size_t)xi * CIN + c3 * 8;
                    v = *(const uint4*)src;
                }
            }
            reg[i] = v;
        }
    };

    issue(0);

#pragma unroll 1
    for (int kzy = 0; kzy < 15; ++kzy) {
        __syncthreads();           // previous phase done reading LDS
        // ds_write staged regs (swizzled position)
#pragma unroll
        for (int i = 0; i < SREG; ++i) {
            const int L = i * NT + t;
            if (L < NLOG) {
                const int pl = (L >= NL) ? 1 : 0;
                const int l2 = L - pl * NL;
                const int x = l2 / KC4;
                const int c3 = l2 - x * KC4;
                const int p = x * RS + (c3 ^ (x & 7));
                *(uint4*)&lds[(pl * PLANE + p) * 8] = reg[i];
            }
        }
        if (kzy + 1 < 15) issue(kzy + 1);   // loads overlap compute below
        __syncthreads();

        const int kz = kzy / 5, ky = kzy - kz * 5;
        const int zz = z + kz - 1, yy = y + ky - 2;
        const bool rv = ((unsigned)zz < (unsigned)S) && ((unsigned)yy < (unsigned)S);
        if (rv) {
            __builtin_amdgcn_s_setprio(1);
#pragma unroll
            for (int kx = 0; kx < 5; ++kx) {
                const int tap = kzy * 5 + kx;
#pragma unroll
                for (int kc = 0; kc < KC; ++kc) {
                    const int c3 = kc * 4 + ci8;
                    bf16x8 bh_[WN], bl_[WN];
#pragma unroll
                    for (int n = 0; n < WN; ++n) {
                        const int co = (waveN * WN + n) * 16 + col;
                        const size_t o = ((size_t)(tap * (CIN / 8) + c3) * COUT + co) * 8;
                        bh_[n] = *(const bf16x8*)(wh + o);
                        bl_[n] = *(const bf16x8*)(wl + o);
                    }
#pragma unroll
                    for (int m = 0; m < WM; ++m) {
                        const int x = (waveM * WM + m) * 16 + col + kx;
                        const int p = x * RS + (c3 ^ (x & 7));
                        bf16x8 a_h = *(const bf16x8*)&lds[p * 8];
                        bf16x8 a_l = *(const bf16x8*)&lds[(PLANE + p) * 8];
#pragma unroll
                        for (int n = 0; n < WN; ++n) {
                            acc[m][n] = __builtin_amdgcn_mfma_f32_16x16x32_bf16(a_h, bh_[n], acc[m][n], 0, 0, 0);
                            acc[m][n] = __builtin_amdgcn_mfma_f32_16x16x32_bf16(a_l, bh_[n], acc[m][n], 0, 0, 0);
                            acc[m][n] = __builtin_amdgcn_mfma_f32_16x16x32_bf16(a_h, bl_[n], acc[m][n], 0, 0, 0);
                        }
                    }
                }
            }
            __builtin_amdgcn_s_setprio(0);
        }
    }

    const int rq = lane >> 4;
    const size_t vb = (size_t)(z * S + y) * S;
#pragma unroll
    for (int m = 0; m < WM; ++m) {
        const int xb = (waveM * WM + m) * 16 + rq * 4;
#pragma unroll
        for (int r = 0; r < 4; ++r) {
            const int x = xb + r;
            const float keep = (mask[vb + x] > 0.f) ? 1.f : 0.f;
#pragma unroll
            for (int n = 0; n < WN; ++n) {
                const int co = (waveN * WN + n) * 16 + col;
                const float v = acc[m][n][r] * keep;
                if (OMODE == 0) {
                    outf[(vb + x) * COUT + co] = v;
                } else {
                    const unsigned short h = f2bf_hi(v);
                    const unsigned short l = f2bf_hi(v - bf2f(h));
                    oh[(vb + x) * COUT + co] = h;
                    ol[(vb + x) * COUT + co] = l;
                }
            }
        }
    }
}

// ---------------------------------------------------------------------------
// Deep-level conv: one block per output voxel.
template<int CIN, int COUT, int S>
__global__ __launch_bounds__(COUT)
void dconv_kernel(const float* __restrict__ in, const float* __restrict__ w,
                  const float* __restrict__ mask, float* __restrict__ out)
{
    __shared__ float buf[CIN];
    const int x = blockIdx.x, y = blockIdx.y, z = blockIdx.z;
    const int co = threadIdx.x;

    float a0 = 0.f, a1 = 0.f, a2 = 0.f, a3 = 0.f;

#pragma unroll 1
    for (int kz = 0; kz < 3; ++kz) {
        const int zz = z + kz - 1;
        if ((unsigned)zz >= (unsigned)S) continue;
#pragma unroll 1
        for (int ky = 0; ky < 5; ++ky) {
            const int yy = y + ky - 2;
            if ((unsigned)yy >= (unsigned)S) continue;
#pragma unroll 1
            for (int kx = 0; kx < 5; ++kx) {
                const int xi = x + kx - 2;
                if ((unsigned)xi >= (unsigned)S) continue;
                const int tap = (kz * 5 + ky) * 5 + kx;
                __syncthreads();
                {
                    const float* src = in + (size_t)((zz * S + yy) * S + xi) * CIN;
                    for (int ci = co; ci < CIN; ci += COUT) buf[ci] = src[ci];
                }
                __syncthreads();
                const float* wp = w + (size_t)tap * CIN * COUT + co;
#pragma unroll 4
                for (int ci = 0; ci < CIN; ci += 4) {
                    a0 += buf[ci + 0] * wp[(size_t)(ci + 0) * COUT];
                    a1 += buf[ci + 1] * wp[(size_t)(ci + 1) * COUT];
                    a2 += buf[ci + 2] * wp[(size_t)(ci + 2) * COUT];
                    a3 += buf[ci + 3] * wp[(size_t)(ci + 3) * COUT];
                }
            }
        }
    }

    const size_t vox = (size_t)(z * S + y) * S + x;
    const float keep = (mask[vox] > 0.f) ? 1.f : 0.f;
    out[vox * COUT + co] = (a0 + a1 + a2 + a3) * keep;
}

// ---------------------------------------------------------------------------
// Sparse maxpool 2x2x2, templated output (0 = fp32, 1 = bf16 hi/lo).
template<int EMIT_BF>
__global__ void pool_kernel2(const float* __restrict__ in, const float* __restrict__ mi,
                             float* __restrict__ outf,
                             unsigned short* __restrict__ oh, unsigned short* __restrict__ ol,
                             float* __restrict__ mo, int S, int C)
{
    const int So = S >> 1;
    const long long total = (long long)So * So * So * C;
    for (long long i = blockIdx.x * (long long)blockDim.x + threadIdx.x; i < total;
         i += (long long)gridDim.x * blockDim.x) {
        const int c = (int)(i % C);
        const long long s = i / C;
        const int xo = (int)(s % So);
        const int yo = (int)((s / So) % So);
        const int zo = (int)(s / ((long long)So * So));
        float best = -1e30f;
        float m2 = 0.f;
        for (int dz = 0; dz < 2; ++dz)
            for (int dy = 0; dy < 2; ++dy)
                for (int dx = 0; dx < 2; ++dx) {
                    const int zi = zo * 2 + dz, yi = yo * 2 + dy, xi = xo * 2 + dx;
                    const float m = mi[(zi * S + yi) * S + xi];
                    if (m > 0.f) {
                        m2 = 1.f;
                        best = fmaxf(best, in[(size_t)((zi * S + yi) * S + xi) * C + c]);
                    }
                }
        const float v = (m2 > 0.f) ? best : 0.f;
        if (EMIT_BF) {
            const unsigned short h = f2bf_hi(v);
            const unsigned short l = f2bf_hi(v - bf2f(h));
            oh[i] = h; ol[i] = l;
        } else {
            outf[i] = v;
        }
        if (c == 0) mo[s] = m2;
    }
}

__global__ __launch_bounds__(256)
void final_kernel(const float* __restrict__ h, const float* __restrict__ mask,
                  const float* __restrict__ w12, const float* __restrict__ w13,
                  float* __restrict__ out)
{
    __shared__ float o1[256];
    const int co = threadIdx.x;
    const float m = (mask[0] > 0.f) ? 1.f : 0.f;
    float a = 0.f;
    for (int ci = 0; ci < 224; ++ci)
        a += h[ci] * w12[(size_t)(37 * 224 + ci) * 256 + co];
    o1[co] = a * m;
    __syncthreads();
    float b = 0.f;
    for (int ci = 0; ci < 256; ++ci)
        b += o1[ci] * w13[(size_t)(37 * 256 + ci) * 256 + co];
    out[co] = b * m;
}

template<int EMIT_BF>
static void pool_launch2(const float* in, const float* mi, float* outf,
                         unsigned short* oh, unsigned short* ol, float* mo,
                         int S, int C, hipStream_t stream)
{
    const long long total = (long long)(S / 2) * (S / 2) * (S / 2) * C;
    long long grid = (total + 255) / 256;
    if (grid > 8192) grid = 8192;
    if (grid < 1) grid = 1;
    pool_kernel2<EMIT_BF><<<(int)grid, 256, 0, stream>>>(in, mi, outf, oh, ol, mo, S, C);
}

// weight-pool element offsets (layers: L0c2, L1c1, L1c2, L2c1, L2c2)
#define OFF0 0
#define OFF1 307200
#define OFF2 768000
#define OFF3 1459200
#define OFF4 2380800

extern "C" void kernel_launch(void* const* d_in, const int* in_sizes, int n_in,
                              void* d_out, int out_size, void* d_ws, size_t ws_size,
                              hipStream_t stream)
{
    const float* feats = (const float*)d_in[0];
    const int*   coors = (const int*)d_in[1];
    const float* w[14];
    for (int i = 0; i < 14; ++i) w[i] = (const float*)d_in[3 + i];
    float* outp = (float*)d_out;

    // ws layout (float units), total ~218 MB (same footprint as round 3)
    float* hA = (float*)d_ws;                    // 16.7M floats
    float* hB = hA + 16777216;                   // 16.7M floats
    float* mA = hB + 16777216;                   // 262144
    float* mB = mA + 262144;                     // 262144
    unsigned short* ah = (unsigned short*)(mB + 262144);   // 16.7M shorts
    unsigned short* al = ah + 16777216;                    // 16.7M shorts
    unsigned short* wh = al + 16777216;                    // 3.6M shorts
    unsigned short* wl = wh + 3609600;
    // aliases into hA (dead after conv1 consumes scatter output):
    unsigned short* bh = (unsigned short*)hA;              // <= 3.2M shorts
    unsigned short* bl = bh + 3211264;
    float* fA = hA + 4194304;                    // deep-level fp32 ping
    float* fB = hA + 5242880;                    // deep-level fp32 pong

    const int npts = in_sizes[0] / 3;

    // weight prep for the 5 MFMA layers
    wprep_kernel<<<256, 256, 0, stream>>>(w[1], wh + OFF0, wl + OFF0, 64, 64);
    wprep_kernel<<<256, 256, 0, stream>>>(w[2], wh + OFF1, wl + OFF1, 64, 96);
    wprep_kernel<<<256, 256, 0, stream>>>(w[3], wh + OFF2, wl + OFF2, 96, 96);
    wprep_kernel<<<256, 256, 0, stream>>>(w[4], wh + OFF3, wl + OFF3, 96, 128);
    wprep_kernel<<<256, 256, 0, stream>>>(w[5], wh + OFF4, wl + OFF4, 128, 128);

    hipMemsetAsync(hA, 0, (size_t)262144 * 3 * sizeof(float), stream);
    hipMemsetAsync(mA, 0, (size_t)262144 * sizeof(float), stream);
    scatter_kernel<<<(npts + 255) / 256, 256, 0, stream>>>(feats, coors, hA, mA, npts);

    // Level 0 (64^3)
    conv1_kernel<<<dim3(64, 64), 256, 0, stream>>>(hA, w[0], mA, ah, al);
    mfma_conv2<64, 64, 64, 2, 2, 2, 2, 0><<<dim3(64, 64), 256, 0, stream>>>(
        ah, al, wh + OFF0, wl + OFF0, mA, hB, nullptr, nullptr);
    pool_launch2<1>(hB, mA, nullptr, ah, al, mB, 64, 64, stream);
    // Level 1 (32^3)
    mfma_conv2<64, 96, 32, 2, 2, 1, 3, 1><<<dim3(32, 32), 192, 0, stream>>>(
        ah, al, wh + OFF1, wl + OFF1, mB, nullptr, bh, bl);
    mfma_conv2<96, 96, 32, 2, 2, 1, 3, 0><<<dim3(32, 32), 192, 0, stream>>>(
        bh, bl, wh + OFF2, wl + OFF2, mB, hB, nullptr, nullptr);
    pool_launch2<1>(hB, mB, nullptr, ah, al, mA, 32, 96, stream);
    // Level 2 (16^3)
    mfma_conv2<96, 128, 16, 1, 2, 1, 4, 1><<<dim3(16, 16), 256, 0, stream>>>(
        ah, al, wh + OFF3, wl + OFF3, mA, nullptr, bh, bl);
    mfma_conv2<128, 128, 16, 1, 2, 1, 4, 0><<<dim3(16, 16), 256, 0, stream>>>(
        bh, bl, wh + OFF4, wl + OFF4, mA, hB, nullptr, nullptr);
    pool_launch2<0>(hB, mA, fA, nullptr, nullptr, mB, 16, 128, stream);
    // Level 3 (8^3)
    dconv_kernel<128, 160, 8><<<dim3(8, 8, 8), 160, 0, stream>>>(fA, w[6], mB, fB);
    dconv_kernel<160, 160, 8><<<dim3(8, 8, 8), 160, 0, stream>>>(fB, w[7], mB, fA);
    pool_launch2<0>(fA, mB, fB, nullptr, nullptr, mA, 8, 160, stream);
    // Level 4 (4^3)
    dconv_kernel<160, 192, 4><<<dim3(4, 4, 4), 192, 0, stream>>>(fB, w[8], mA, fA);
    dconv_kernel<192, 192, 4><<<dim3(4, 4, 4), 192, 0, stream>>>(fA, w[9], mA, fB);
    pool_launch2<0>(fB, mA, fA, nullptr, nullptr, mB, 4, 192, stream);
    // Level 5 (2^3)
    dconv_kernel<192, 224, 2><<<dim3(2, 2, 2), 224, 0, stream>>>(fA, w[10], mB, fB);
    dconv_kernel<224, 224, 2><<<dim3(2, 2, 2), 224, 0, stream>>>(fB, w[11], mB, fA);
    pool_launch2<0>(fA, mB, fB, nullptr, nullptr, mA, 2, 224, stream);
    // Final 1x1x1 convs (center tap only)
    final_kernel<<<1, 256, 0, stream>>>(fB, mA, w[12], w[13], outp);
}

// Round 5
// 1570.065 us; speedup vs baseline: 8.3512x; 1.1854x over previous
//
#include <hip/hip_runtime.h>
#include <hip/hip_bf16.h>
#include <cstdint>

typedef __attribute__((ext_vector_type(8))) short bf16x8;
typedef __attribute__((ext_vector_type(4))) float f32x4;

__device__ __forceinline__ unsigned short f2bf_hi(float v) {
    unsigned u = __float_as_uint(v);
    u = u + 0x7fffu + ((u >> 16) & 1u);
    return (unsigned short)(u >> 16);
}
__device__ __forceinline__ float bf2f(unsigned short h) {
    return __uint_as_float(((unsigned)h) << 16);
}

// ---------------------------------------------------------------------------
__global__ void scatter_kernel(const float* __restrict__ feats,
                               const int* __restrict__ coors,
                               float* __restrict__ dense,
                               float* __restrict__ mask, int n)
{
    int i = blockIdx.x * blockDim.x + threadIdx.x;
    if (i >= n) return;
    const int z = coors[i * 4 + 1];
    const int y = coors[i * 4 + 2];
    const int x = coors[i * 4 + 3];
    const size_t s = (size_t)((z * 64 + y) * 64 + x);
    dense[s * 3 + 0] = feats[i * 3 + 0];
    dense[s * 3 + 1] = feats[i * 3 + 1];
    dense[s * 3 + 2] = feats[i * 3 + 2];
    mask[s] = 1.f;
}

// weights [tap(75)][ci][co] fp32 -> split bf16 interleaved MFMA layout:
// wv[((tap*(CI/8)+ci8)*CO + co)*16 + {0..7}=hi, {8..15}=lo]
__global__ void wprep_kernel(const float* __restrict__ w,
                             unsigned short* __restrict__ wv, int CI, int CO)
{
    const int total = 75 * CI * CO;
    const int stride = gridDim.x * blockDim.x;
    for (int i = blockIdx.x * blockDim.x + threadIdx.x; i < total; i += stride) {
        const int tap = i / (CI * CO);
        const int r = i - tap * CI * CO;
        const int ci = r / CO;
        const int co = r - ci * CO;
        const float v = w[i];
        const unsigned short h = f2bf_hi(v);
        const unsigned short l = f2bf_hi(v - bf2f(h));
        const size_t o = ((size_t)(tap * (CI / 8) + (ci >> 3)) * CO + co) * 16 + (ci & 7);
        wv[o] = h; wv[o + 8] = l;
    }
}

// ---------------------------------------------------------------------------
// L0 conv1: CIN=3, COUT=64, S=64. Planar LDS, fused single-bf16 output.
__global__ __launch_bounds__(256)
void conv1_kernel(const float* __restrict__ in, const float* __restrict__ w,
                  const float* __restrict__ mask, unsigned short* __restrict__ ob)
{
    constexpr int S = 64, SP = 68;
    __shared__ float lds[15][3][SP];

    const int bid = blockIdx.y * S + blockIdx.x;
    const int wg = (bid & 7) * (S * S / 8) + (bid >> 3);   // XCD-chunked
    const int y = wg & 63, z = wg >> 6;
    const int t = threadIdx.x;

    for (int idx = t; idx < 15 * 3 * SP; idx += 256) {
        const int r = idx / (3 * SP);
        const int rem = idx - r * 3 * SP;
        const int ci = rem / SP;
        const int x = rem - ci * SP;
        const int kz = r / 5, ky = r - kz * 5;
        const int zz = z + kz - 1, yy = y + ky - 2, xi = x - 2;
        float v = 0.f;
        if ((unsigned)zz < (unsigned)S && (unsigned)yy < (unsigned)S && (unsigned)xi < (unsigned)S)
            v = in[(size_t)((zz * S + yy) * S + xi) * 3 + ci];
        lds[r][ci][x] = v;
    }
    __syncthreads();

    const int co = t & 63, xs = t >> 6;
    float acc[16];
#pragma unroll
    for (int i = 0; i < 16; ++i) acc[i] = 0.f;

#pragma unroll 1
    for (int r = 0; r < 15; ++r) {
#pragma unroll
        for (int ci = 0; ci < 3; ++ci) {
            float inv[20];
#pragma unroll
            for (int j = 0; j < 5; ++j)
                *(float4*)&inv[j * 4] = *(const float4*)&lds[r][ci][xs * 16 + j * 4];
            const float* wp = w + (size_t)(r * 15 + ci) * 64 + co;
#pragma unroll
            for (int kx = 0; kx < 5; ++kx) {
                const float wv = wp[kx * 192];
#pragma unroll
                for (int i = 0; i < 16; ++i) acc[i] += inv[i + kx] * wv;
            }
        }
    }

    const size_t vb = (size_t)(z * S + y) * S;
#pragma unroll
    for (int i = 0; i < 16; ++i) {
        const int x = xs * 16 + i;
        const float keep = (mask[vb + x] > 0.f) ? 1.f : 0.f;
        ob[(vb + x) * 64 + co] = f2bf_hi(acc[i] * keep);
    }
}

// ---------------------------------------------------------------------------
// MFMA conv v3: single-bf16 activations x split-bf16 weights (2 MFMA/tap).
// Reg-staged pipeline, XOR-swizzled LDS, XCD block swizzle, setprio.
// OMODE: 0 = fp32 out, 1 = bf16 out.
template<int CIN, int COUT, int S, int WM, int WN, int MG, int NG, int OMODE>
__global__ __launch_bounds__(MG * NG * 64)
void mfma_conv3(const unsigned short* __restrict__ ab,
                const unsigned short* __restrict__ wv,
                const float* __restrict__ mask, float* __restrict__ outf,
                unsigned short* __restrict__ outb)
{
    constexpr int SP = S + 4;
    constexpr int KC = CIN / 32;
    constexpr int KC4 = CIN / 8;                // 16B chunks per x
    constexpr int RS = (KC4 <= 8) ? 8 : 16;     // padded (pow2)
    constexpr int PLANE = SP * RS;
    constexpr int NL = SP * KC4;                // logical chunks
    constexpr int NT = MG * NG * 64;
    constexpr int SREG = (NL + NT - 1) / NT;
    static_assert(S / 16 == WM * MG && COUT / 16 == WN * NG, "geometry");

    __shared__ unsigned short lds[PLANE * 8];

    const int bid = blockIdx.y * S + blockIdx.x;
    const int wg = (bid & 7) * (S * S / 8) + (bid >> 3);
    const int y = wg % S, z = wg / S;

    const int t = threadIdx.x;
    const int lane = t & 63;
    const int wave = t >> 6;
    const int waveM = wave % MG;
    const int waveN = wave / MG;
    const int col = lane & 15;
    const int ci8 = lane >> 4;

    f32x4 acc[WM][WN];
    const f32x4 vzero = {0.f, 0.f, 0.f, 0.f};
#pragma unroll
    for (int m = 0; m < WM; ++m)
#pragma unroll
        for (int n = 0; n < WN; ++n) acc[m][n] = vzero;

    uint4 reg[SREG];

    auto issue = [&](int kzy) {
        const int kz = kzy / 5, ky = kzy - kz * 5;
        const int zz = z + kz - 1, yy = y + ky - 2;
        const bool rv = ((unsigned)zz < (unsigned)S) && ((unsigned)yy < (unsigned)S);
        const size_t rowbase = rv ? (size_t)((zz * S + yy) * S) * CIN : 0;
#pragma unroll
        for (int i = 0; i < SREG; ++i) {
            const int L = i * NT + t;
            uint4 v = {0u, 0u, 0u, 0u};
            if (L < NL) {
                const int x = L / KC4;
                const int c3 = L - x * KC4;
                const int xi = x - 2;
                if (rv && (unsigned)xi < (unsigned)S)
                    v = *(const uint4*)(ab + rowbase + (size_t)xi * CIN + c3 * 8);
            }
            reg[i] = v;
        }
    };

    issue(0);

#pragma unroll 1
    for (int kzy = 0; kzy < 15; ++kzy) {
        __syncthreads();
#pragma unroll
        for (int i = 0; i < SREG; ++i) {
            const int L = i * NT + t;
            if (L < NL) {
                const int x = L / KC4;
                const int c3 = L - x * KC4;
                const int p = x * RS + (c3 ^ (x & 7));
                *(uint4*)&lds[p * 8] = reg[i];
            }
        }
        if (kzy + 1 < 15) issue(kzy + 1);
        __syncthreads();

        const int kz = kzy / 5, ky = kzy - kz * 5;
        const int zz = z + kz - 1, yy = y + ky - 2;
        if (((unsigned)zz < (unsigned)S) && ((unsigned)yy < (unsigned)S)) {
            __builtin_amdgcn_s_setprio(1);
#pragma unroll
            for (int kx = 0; kx < 5; ++kx) {
                const int tap = kzy * 5 + kx;
#pragma unroll
                for (int kc = 0; kc < KC; ++kc) {
                    const int c3 = kc * 4 + ci8;
                    bf16x8 wh_[WN], wl_[WN];
#pragma unroll
                    for (int n = 0; n < WN; ++n) {
                        const int co = (waveN * WN + n) * 16 + col;
                        const size_t o = ((size_t)(tap * KC4 + c3) * COUT + co) * 16;
                        wh_[n] = *(const bf16x8*)(wv + o);
                        wl_[n] = *(const bf16x8*)(wv + o + 8);
                    }
#pragma unroll
                    for (int m = 0; m < WM; ++m) {
                        const int x = (waveM * WM + m) * 16 + col + kx;
                        const int p = x * RS + (c3 ^ (x & 7));
                        bf16x8 a = *(const bf16x8*)&lds[p * 8];
#pragma unroll
                        for (int n = 0; n < WN; ++n) {
                            acc[m][n] = __builtin_amdgcn_mfma_f32_16x16x32_bf16(a, wh_[n], acc[m][n], 0, 0, 0);
                            acc[m][n] = __builtin_amdgcn_mfma_f32_16x16x32_bf16(a, wl_[n], acc[m][n], 0, 0, 0);
                        }
                    }
                }
            }
            __builtin_amdgcn_s_setprio(0);
        }
    }

    const int rq = lane >> 4;
    const size_t vb = (size_t)(z * S + y) * S;
#pragma unroll
    for (int m = 0; m < WM; ++m) {
        const int xb = (waveM * WM + m) * 16 + rq * 4;
#pragma unroll
        for (int r = 0; r < 4; ++r) {
            const int x = xb + r;
            const float keep = (mask[vb + x] > 0.f) ? 1.f : 0.f;
#pragma unroll
            for (int n = 0; n < WN; ++n) {
                const int co = (waveN * WN + n) * 16 + col;
                const float v = acc[m][n][r] * keep;
                if (OMODE == 0) outf[(vb + x) * COUT + co] = v;
                else            outb[(vb + x) * COUT + co] = f2bf_hi(v);
            }
        }
    }
}

// ---------------------------------------------------------------------------
// Deep-level conv: one block per output voxel.
template<int CIN, int COUT, int S>
__global__ __launch_bounds__(COUT)
void dconv_kernel(const float* __restrict__ in, const float* __restrict__ w,
                  const float* __restrict__ mask, float* __restrict__ out)
{
    __shared__ float buf[CIN];
    const int x = blockIdx.x, y = blockIdx.y, z = blockIdx.z;
    const int co = threadIdx.x;

    float a0 = 0.f, a1 = 0.f, a2 = 0.f, a3 = 0.f;

#pragma unroll 1
    for (int kz = 0; kz < 3; ++kz) {
        const int zz = z + kz - 1;
        if ((unsigned)zz >= (unsigned)S) continue;
#pragma unroll 1
        for (int ky = 0; ky < 5; ++ky) {
            const int yy = y + ky - 2;
            if ((unsigned)yy >= (unsigned)S) continue;
#pragma unroll 1
            for (int kx = 0; kx < 5; ++kx) {
                const int xi = x + kx - 2;
                if ((unsigned)xi >= (unsigned)S) continue;
                const int tap = (kz * 5 + ky) * 5 + kx;
                __syncthreads();
                {
                    const float* src = in + (size_t)((zz * S + yy) * S + xi) * CIN;
                    for (int ci = co; ci < CIN; ci += COUT) buf[ci] = src[ci];
                }
                __syncthreads();
                const float* wp = w + (size_t)tap * CIN * COUT + co;
#pragma unroll 4
                for (int ci = 0; ci < CIN; ci += 4) {
                    a0 += buf[ci + 0] * wp[(size_t)(ci + 0) * COUT];
                    a1 += buf[ci + 1] * wp[(size_t)(ci + 1) * COUT];
                    a2 += buf[ci + 2] * wp[(size_t)(ci + 2) * COUT];
                    a3 += buf[ci + 3] * wp[(size_t)(ci + 3) * COUT];
                }
            }
        }
    }

    const size_t vox = (size_t)(z * S + y) * S + x;
    const float keep = (mask[vox] > 0.f) ? 1.f : 0.f;
    out[vox * COUT + co] = (a0 + a1 + a2 + a3) * keep;
}

// ---------------------------------------------------------------------------
// Sparse maxpool 2x2x2; IN_BF/OUT_BF select bf16 or fp32 streams.
template<int IN_BF, int OUT_BF>
__global__ void pool_kernel3(const float* __restrict__ inf,
                             const unsigned short* __restrict__ inb,
                             const float* __restrict__ mi,
                             float* __restrict__ outf, unsigned short* __restrict__ outb,
                             float* __restrict__ mo, int S, int C)
{
    const int So = S >> 1;
    const long long total = (long long)So * So * So * C;
    for (long long i = blockIdx.x * (long long)blockDim.x + threadIdx.x; i < total;
         i += (long long)gridDim.x * blockDim.x) {
        const int c = (int)(i % C);
        const long long s = i / C;
        const int xo = (int)(s % So);
        const int yo = (int)((s / So) % So);
        const int zo = (int)(s / ((long long)So * So));
        float best = -1e30f;
        float m2 = 0.f;
        for (int dz = 0; dz < 2; ++dz)
            for (int dy = 0; dy < 2; ++dy)
                for (int dx = 0; dx < 2; ++dx) {
                    const int zi = zo * 2 + dz, yi = yo * 2 + dy, xi = xo * 2 + dx;
                    const float m = mi[(zi * S + yi) * S + xi];
                    if (m > 0.f) {
                        m2 = 1.f;
                        const size_t idx = (size_t)((zi * S + yi) * S + xi) * C + c;
                        const float v = IN_BF ? bf2f(inb[idx]) : inf[idx];
                        best = fmaxf(best, v);
                    }
                }
        const float v = (m2 > 0.f) ? best : 0.f;
        if (OUT_BF) outb[i] = f2bf_hi(v);
        else        outf[i] = v;
        if (c == 0) mo[s] = m2;
    }
}

__global__ __launch_bounds__(256)
void final_kernel(const float* __restrict__ h, const float* __restrict__ mask,
                  const float* __restrict__ w12, const float* __restrict__ w13,
                  float* __restrict__ out)
{
    __shared__ float o1[256];
    const int co = threadIdx.x;
    const float m = (mask[0] > 0.f) ? 1.f : 0.f;
    float a = 0.f;
    for (int ci = 0; ci < 224; ++ci)
        a += h[ci] * w12[(size_t)(37 * 224 + ci) * 256 + co];
    o1[co] = a * m;
    __syncthreads();
    float b = 0.f;
    for (int ci = 0; ci < 256; ++ci)
        b += o1[ci] * w13[(size_t)(37 * 256 + ci) * 256 + co];
    out[co] = b * m;
}

template<int IN_BF, int OUT_BF>
static void pool_launch3(const float* inf, const unsigned short* inb, const float* mi,
                         float* outf, unsigned short* outb, float* mo,
                         int S, int C, hipStream_t stream)
{
    const long long total = (long long)(S / 2) * (S / 2) * (S / 2) * C;
    long long grid = (total + 255) / 256;
    if (grid > 8192) grid = 8192;
    if (grid < 1) grid = 1;
    pool_kernel3<IN_BF, OUT_BF><<<(int)grid, 256, 0, stream>>>(inf, inb, mi, outf, outb, mo, S, C);
}

// weight-pool element offsets (shorts): L0c2, L1c1, L1c2, L2c1, L2c2
#define WOFF0 0
#define WOFF1 614400
#define WOFF2 1536000
#define WOFF3 2918400
#define WOFF4 4761600

extern "C" void kernel_launch(void* const* d_in, const int* in_sizes, int n_in,
                              void* d_out, int out_size, void* d_ws, size_t ws_size,
                              hipStream_t stream)
{
    const float* feats = (const float*)d_in[0];
    const int*   coors = (const int*)d_in[1];
    const float* w[14];
    for (int i = 0; i < 14; ++i) w[i] = (const float*)d_in[3 + i];
    float* outp = (float*)d_out;

    // ws layout
    float* dense0 = (float*)d_ws;                 // 786432 floats
    float* mA = dense0 + 786432;                  // 262144
    float* mB = mA + 262144;                      // 262144
    float* fA = mB + 262144;                      // 524288
    float* fB = fA + 524288;                      // 524288
    unsigned short* ab = (unsigned short*)(fB + 524288);   // 16.7M shorts
    unsigned short* bb = ab + 16777216;                    // 16.7M shorts
    unsigned short* wvp = bb + 16777216;                   // 7.2M shorts

    const int npts = in_sizes[0] / 3;

    // weight prep (split bf16, interleaved)
    wprep_kernel<<<256, 256, 0, stream>>>(w[1], wvp + WOFF0, 64, 64);
    wprep_kernel<<<256, 256, 0, stream>>>(w[2], wvp + WOFF1, 64, 96);
    wprep_kernel<<<256, 256, 0, stream>>>(w[3], wvp + WOFF2, 96, 96);
    wprep_kernel<<<256, 256, 0, stream>>>(w[4], wvp + WOFF3, 96, 128);
    wprep_kernel<<<256, 256, 0, stream>>>(w[5], wvp + WOFF4, 128, 128);

    hipMemsetAsync(dense0, 0, (size_t)786432 * sizeof(float), stream);
    hipMemsetAsync(mA, 0, (size_t)262144 * sizeof(float), stream);
    scatter_kernel<<<(npts + 255) / 256, 256, 0, stream>>>(feats, coors, dense0, mA, npts);

    // Level 0 (64^3)
    conv1_kernel<<<dim3(64, 64), 256, 0, stream>>>(dense0, w[0], mA, ab);
    mfma_conv3<64, 64, 64, 2, 2, 2, 2, 1><<<dim3(64, 64), 256, 0, stream>>>(
        ab, wvp + WOFF0, mA, nullptr, bb);
    pool_launch3<1, 1>(nullptr, bb, mA, nullptr, ab, mB, 64, 64, stream);
    // Level 1 (32^3)
    mfma_conv3<64, 96, 32, 2, 2, 1, 3, 1><<<dim3(32, 32), 192, 0, stream>>>(
        ab, wvp + WOFF1, mB, nullptr, bb);
    mfma_conv3<96, 96, 32, 2, 2, 1, 3, 1><<<dim3(32, 32), 192, 0, stream>>>(
        bb, wvp + WOFF2, mB, nullptr, ab);
    pool_launch3<1, 1>(nullptr, ab, mB, nullptr, bb, mA, 32, 96, stream);
    // Level 2 (16^3)
    mfma_conv3<96, 128, 16, 1, 2, 1, 4, 1><<<dim3(16, 16), 256, 0, stream>>>(
        bb, wvp + WOFF3, mA, nullptr, ab);
    mfma_conv3<128, 128, 16, 1, 2, 1, 4, 0><<<dim3(16, 16), 256, 0, stream>>>(
        ab, wvp + WOFF4, mA, fA, nullptr);
    pool_launch3<0, 0>(fA, nullptr, mA, fB, nullptr, mB, 16, 128, stream);
    // Level 3 (8^3)
    dconv_kernel<128, 160, 8><<<dim3(8, 8, 8), 160, 0, stream>>>(fB, w[6], mB, fA);
    dconv_kernel<160, 160, 8><<<dim3(8, 8, 8), 160, 0, stream>>>(fA, w[7], mB, fB);
    pool_launch3<0, 0>(fB, nullptr, mB, fA, nullptr, mA, 8, 160, stream);
    // Level 4 (4^3)
    dconv_kernel<160, 192, 4><<<dim3(4, 4, 4), 192, 0, stream>>>(fA, w[8], mA, fB);
    dconv_kernel<192, 192, 4><<<dim3(4, 4, 4), 192, 0, stream>>>(fB, w[9], mA, fA);
    pool_launch3<0, 0>(fA, nullptr, mA, fB, nullptr, mB, 4, 192, stream);
    // Level 5 (2^3)
    dconv_kernel<192, 224, 2><<<dim3(2, 2, 2), 224, 0, stream>>>(fB, w[10], mB, fA);
    dconv_kernel<224, 224, 2><<<dim3(2, 2, 2), 224, 0, stream>>>(fA, w[11], mB, fB);
    pool_launch3<0, 0>(fB, nullptr, mB, fA, nullptr, mA, 2, 224, stream);
    // Final 1x1x1 convs (center tap only)
    final_kernel<<<1, 256, 0, stream>>>(fA, mA, w[12], w[13], outp);
}